// Round 4
// baseline (35.336 us; speedup 1.0000x reference)
//
#include <hip/hip_runtime.h>

// Problem constants (B, C, O, K, H, W) = (8, 64, 64, 3, 128, 128)
#define NTAP 9
#define C_DIM 64
#define O_DIM 64
#define HW 128
#define CPAD 72   // LDS w-row stride 144B: 16B-aligned, inherent-min bank pattern

typedef short s16x8 __attribute__((ext_vector_type(8)));
typedef float f32x16 __attribute__((ext_vector_type(16)));

__device__ __forceinline__ unsigned short f2bf(float x) {
    unsigned int u = __float_as_uint(x);
    unsigned int r = (u + 0x7fffu + ((u >> 16) & 1u)) >> 16;
    return (unsigned short)r;
}

// ---------------------------------------------------------------------------
// Pre-kernel: W [C=64][3][3][O=64] f32 -> fragment-major bf16 (d_ws, 72KB).
// Fragment F = ((tap*4 + s)*2 + m)*64 + lane, element e:
//   c = 16*s + 8*(lane>>5) + e,   o = 32*m + (lane&31)
// Same (lane>>5, e) -> k-slot mapping is used for the feat (B) operand, so the
// contraction is correct under any hardware k-slot permutation.
// ---------------------------------------------------------------------------
__global__ void swizzle_W_kernel(const float* __restrict__ W,
                                 unsigned short* __restrict__ Wf) {
    int idx = blockIdx.x * 256 + threadIdx.x;
    if (idx >= NTAP * 4 * 2 * 64 * 8) return;
    int e    = idx & 7;
    int lane = (idx >> 3) & 63;
    int m    = (idx >> 9) & 1;
    int s    = (idx >> 10) & 3;
    int tap  = idx >> 12;
    int c = s * 16 + ((lane >> 5) << 3) + e;
    int o = (m << 5) + (lane & 31);
    Wf[idx] = f2bf(W[c * 576 + tap * 64 + o]);
}

// ---------------------------------------------------------------------------
// Main kernel: one block per (batch, 8h x 16w patch). 256 threads = 4 waves.
// LDS window: 10 rows x 18 w x 64 c bf16 (25.9KB) -> 5 blocks/CU co-resident.
// Wave v: MFMA B-columns = pixel group {rows 2v,2v+1} x {w0..w0+15}, all 64 o.
// out[o][px] = sum_tap tm[tap][px] * (W_tap^T . feat_window[px + shift])
// ---------------------------------------------------------------------------
__global__ __launch_bounds__(256, 5) void dyconv_kernel(
    const float* __restrict__ feat, const float* __restrict__ tm,
    const unsigned short* __restrict__ Wf, float* __restrict__ out)
{
    __shared__ __align__(16) unsigned short feat_lds[10][18][CPAD];

    // bijective XCD swizzle: XCD x gets batch x; w-neighbors adjacent in time
    const int flat  = blockIdx.x;            // 0..1023
    const int b     = flat & 7;
    const int inner = flat >> 3;              // 0..127
    const int h0    = (inner >> 3) * 8;       // 0..120
    const int w0    = (inner & 7) * 16;       // 0..112

    const int tid = threadIdx.x;

    // ---- stage core: 10 rows x 16 w x 64 c, tiles of (4w x 8c) ----
    for (int T = tid; T < 320; T += 256) {
        const int r    = T >> 5;              // input row 0..9 (hr = h0-1+r)
        const int rem  = T & 31;
        const int wg   = rem & 3;             // w-quad: w = w0 + wg*4 + i
        const int coct = rem >> 2;            // c-octet: c = coct*8 + j
        const int hr   = h0 - 1 + r;
        const bool inb = (hr >= 0) && (hr < HW);
        const float* src = feat + (((size_t)(b * C_DIM + coct * 8)) * HW + hr) * HW
                         + w0 + wg * 4;
        float4 v[8];
        #pragma unroll
        for (int j = 0; j < 8; ++j)
            v[j] = inb ? *(const float4*)(src + (size_t)j * (HW * HW))
                       : float4{0.f, 0.f, 0.f, 0.f};
        #pragma unroll
        for (int i = 0; i < 4; ++i) {
            s16x8 pk;
            #pragma unroll
            for (int j = 0; j < 8; ++j) {
                const float* vf = (const float*)&v[j];
                pk[j] = (short)f2bf(vf[i]);
            }
            *(s16x8*)&feat_lds[r][wg * 4 + i + 1][coct * 8] = pk;
        }
    }
    // ---- stage halo columns: w = w0-1 (windex 0) and w = w0+16 (windex 17) ----
    for (int i = tid; i < 1280; i += 256) {
        const int r    = i >> 7;               // 0..9
        const int rem  = i & 127;
        const int c    = rem & 63;
        const int side = rem >> 6;              // 0: w0-1, 1: w0+16
        const int hr   = h0 - 1 + r;
        const int gw   = w0 + (side ? 16 : -1);
        float v = 0.f;
        if (hr >= 0 && hr < HW && gw >= 0 && gw < HW)
            v = feat[(((size_t)(b * C_DIM + c)) * HW + hr) * HW + gw];
        feat_lds[r][side ? 17 : 0][c] = f2bf(v);
    }

    const int lane = tid & 63;
    const int wave = tid >> 6;                 // 0..3
    const int g    = lane >> 5;                // k-slot half
    const int c31  = lane & 31;                // MFMA column = pixel index
    const int prow = c31 >> 4;                 // pixel row within pair
    const int pw   = c31 & 15;                 // pixel w within patch
    const int hout = h0 + wave * 2 + prow;
    const int wout = w0 + pw;
    const int lrow = wave * 2 + prow;          // base LDS row for di=0

    __syncthreads();

    const s16x8* __restrict__ Wf8 = (const s16x8*)Wf;

    f32x16 acc0 = {0,0,0,0,0,0,0,0,0,0,0,0,0,0,0,0};
    f32x16 acc1 = acc0;

    #pragma unroll
    for (int tap = 0; tap < NTAP; ++tap) {
        const int di = tap / 3;
        const int dj = tap % 3;
        const s16x8* bp = (const s16x8*)&feat_lds[lrow + di][pw + dj][0];
        const float tv = tm[((size_t)(b * NTAP + tap)) * (HW * HW)
                            + (size_t)hout * HW + wout];
        f32x16 pa = {0,0,0,0,0,0,0,0,0,0,0,0,0,0,0,0};
        f32x16 pb = pa;
        #pragma unroll
        for (int s = 0; s < 4; ++s) {
            s16x8 bf = bp[2 * s + g];
            s16x8 a0 = Wf8[((tap * 4 + s) * 2 + 0) * 64 + lane];
            s16x8 a1 = Wf8[((tap * 4 + s) * 2 + 1) * 64 + lane];
            pa = __builtin_amdgcn_mfma_f32_32x32x16_bf16(a0, bf, pa, 0, 0, 0);
            pb = __builtin_amdgcn_mfma_f32_32x32x16_bf16(a1, bf, pb, 0, 0, 0);
        }
        #pragma unroll
        for (int r = 0; r < 16; ++r) {
            acc0[r] = fmaf(tv, pa[r], acc0[r]);
            acc1[r] = fmaf(tv, pb[r], acc1[r]);
        }
    }

    // ---- store: D (32x32) layout: col = lane&31 (pixel), row o = (r&3)+8*(r>>2)+4*g
    float* op = out + ((size_t)b * O_DIM) * (HW * HW) + (size_t)hout * HW + wout;
    #pragma unroll
    for (int r = 0; r < 16; ++r) {
        const int o = (r & 3) + ((r >> 2) << 3) + (g << 2);
        op[(size_t)o        * (HW * HW)] = acc0[r];
        op[(size_t)(o + 32) * (HW * HW)] = acc1[r];
    }
}

extern "C" void kernel_launch(void* const* d_in, const int* in_sizes, int n_in,
                              void* d_out, int out_size, void* d_ws, size_t ws_size,
                              hipStream_t stream) {
    const float* feat = (const float*)d_in[0];   // [8,64,128,128] f32
    const float* tm   = (const float*)d_in[1];   // [8,9,16384]    f32
    const float* W    = (const float*)d_in[2];   // [64,3,3,64]    f32
    float* out        = (float*)d_out;           // [8,64,128,128] f32
    unsigned short* Wf = (unsigned short*)d_ws;  // 73728 B scratch

    swizzle_W_kernel<<<dim3(144), dim3(256), 0, stream>>>(W, Wf);
    dyconv_kernel<<<dim3(1024), dim3(256), 0, stream>>>(feat, tm, Wf, out);
}

// Round 5
// 35.152 us; speedup vs baseline: 1.0053x; 1.0053x over previous
//
#include <hip/hip_runtime.h>

// Problem constants (B, C, O, K, H, W) = (8, 64, 64, 3, 128, 128)
#define NTAP 9
#define C_DIM 64
#define O_DIM 64
#define HW 128
#define CPAD 72   // LDS w-row stride 144B: 16B-aligned, inherent-min bank pattern

typedef short s16x8 __attribute__((ext_vector_type(8)));
typedef float f32x16 __attribute__((ext_vector_type(16)));

__device__ __forceinline__ unsigned short f2bf(float x) {
    unsigned int u = __float_as_uint(x);
    unsigned int r = (u + 0x7fffu + ((u >> 16) & 1u)) >> 16;
    return (unsigned short)r;
}

// ---------------------------------------------------------------------------
// Pre-kernel: W [C=64][3][3][O=64] f32 -> fragment-major bf16 (d_ws, 72KB).
// Fragment F = ((tap*4 + s)*2 + m)*64 + lane, element e:
//   c = 16*s + 8*(lane>>5) + e,   o = 32*m + (lane&31)
// Same (lane>>5, e) -> k-slot mapping is used for the feat (B) operand, so the
// contraction is correct under any hardware k-slot permutation.
// ---------------------------------------------------------------------------
__global__ void swizzle_W_kernel(const float* __restrict__ W,
                                 unsigned short* __restrict__ Wf) {
    int idx = blockIdx.x * 256 + threadIdx.x;
    if (idx >= NTAP * 4 * 2 * 64 * 8) return;
    int e    = idx & 7;
    int lane = (idx >> 3) & 63;
    int m    = (idx >> 9) & 1;
    int s    = (idx >> 10) & 3;
    int tap  = idx >> 12;
    int c = s * 16 + ((lane >> 5) << 3) + e;
    int o = (m << 5) + (lane & 31);
    Wf[idx] = f2bf(W[c * 576 + tap * 64 + o]);
}

// ---------------------------------------------------------------------------
// Main kernel: one block per (batch, 8h x 16w patch). 256 threads = 4 waves.
// LDS window: 10 rows x 18 w x 64 c bf16 (25.9KB) -> 5 blocks/CU co-resident.
// Wave v: MFMA B-columns = pixel group {rows 2v,2v+1} x {w0..w0+15}, all 64 o.
// out[o][px] = sum_tap tm[tap][px] * (W_tap^T . feat_window[px + shift])
// ---------------------------------------------------------------------------
__global__ __launch_bounds__(256, 5) void dyconv_kernel(
    const float* __restrict__ feat, const float* __restrict__ tm,
    const unsigned short* __restrict__ Wf, float* __restrict__ out)
{
    __shared__ __align__(16) unsigned short feat_lds[10][18][CPAD];

    // bijective XCD swizzle: XCD x gets batch x; w-neighbors adjacent in time
    const int flat  = blockIdx.x;            // 0..1023
    const int b     = flat & 7;
    const int inner = flat >> 3;              // 0..127
    const int h0    = (inner >> 3) * 8;       // 0..120
    const int w0    = (inner & 7) * 16;       // 0..112

    const int tid = threadIdx.x;

    // ---- stage core: 10 rows x 16 w x 64 c, tiles of (4w x 8c) ----
    for (int T = tid; T < 320; T += 256) {
        const int r    = T >> 5;              // input row 0..9 (hr = h0-1+r)
        const int rem  = T & 31;
        const int wg   = rem & 3;             // w-quad: w = w0 + wg*4 + i
        const int coct = rem >> 2;            // c-octet: c = coct*8 + j
        const int hr   = h0 - 1 + r;
        const bool inb = (hr >= 0) && (hr < HW);
        const float* src = feat + (((size_t)(b * C_DIM + coct * 8)) * HW + hr) * HW
                         + w0 + wg * 4;
        float4 v[8];
        #pragma unroll
        for (int j = 0; j < 8; ++j)
            v[j] = inb ? *(const float4*)(src + (size_t)j * (HW * HW))
                       : float4{0.f, 0.f, 0.f, 0.f};
        #pragma unroll
        for (int i = 0; i < 4; ++i) {
            s16x8 pk;
            #pragma unroll
            for (int j = 0; j < 8; ++j) {
                const float* vf = (const float*)&v[j];
                pk[j] = (short)f2bf(vf[i]);
            }
            *(s16x8*)&feat_lds[r][wg * 4 + i + 1][coct * 8] = pk;
        }
    }
    // ---- stage halo columns: w = w0-1 (windex 0) and w = w0+16 (windex 17) ----
    for (int i = tid; i < 1280; i += 256) {
        const int r    = i >> 7;               // 0..9
        const int rem  = i & 127;
        const int c    = rem & 63;
        const int side = rem >> 6;              // 0: w0-1, 1: w0+16
        const int hr   = h0 - 1 + r;
        const int gw   = w0 + (side ? 16 : -1);
        float v = 0.f;
        if (hr >= 0 && hr < HW && gw >= 0 && gw < HW)
            v = feat[(((size_t)(b * C_DIM + c)) * HW + hr) * HW + gw];
        feat_lds[r][side ? 17 : 0][c] = f2bf(v);
    }

    const int lane = tid & 63;
    const int wave = tid >> 6;                 // 0..3
    const int g    = lane >> 5;                // k-slot half
    const int c31  = lane & 31;                // MFMA column = pixel index
    const int prow = c31 >> 4;                 // pixel row within pair
    const int pw   = c31 & 15;                 // pixel w within patch
    const int hout = h0 + wave * 2 + prow;
    const int wout = w0 + pw;
    const int lrow = wave * 2 + prow;          // base LDS row for di=0

    __syncthreads();

    const s16x8* __restrict__ Wf8 = (const s16x8*)Wf;

    f32x16 acc0 = {0,0,0,0,0,0,0,0,0,0,0,0,0,0,0,0};
    f32x16 acc1 = acc0;

    #pragma unroll
    for (int tap = 0; tap < NTAP; ++tap) {
        const int di = tap / 3;
        const int dj = tap % 3;
        const s16x8* bp = (const s16x8*)&feat_lds[lrow + di][pw + dj][0];
        const float tv = tm[((size_t)(b * NTAP + tap)) * (HW * HW)
                            + (size_t)hout * HW + wout];
        f32x16 pa = {0,0,0,0,0,0,0,0,0,0,0,0,0,0,0,0};
        f32x16 pb = pa;
        #pragma unroll
        for (int s = 0; s < 4; ++s) {
            s16x8 bf = bp[2 * s + g];
            s16x8 a0 = Wf8[((tap * 4 + s) * 2 + 0) * 64 + lane];
            s16x8 a1 = Wf8[((tap * 4 + s) * 2 + 1) * 64 + lane];
            pa = __builtin_amdgcn_mfma_f32_32x32x16_bf16(a0, bf, pa, 0, 0, 0);
            pb = __builtin_amdgcn_mfma_f32_32x32x16_bf16(a1, bf, pb, 0, 0, 0);
        }
        #pragma unroll
        for (int r = 0; r < 16; ++r) {
            acc0[r] = fmaf(tv, pa[r], acc0[r]);
            acc1[r] = fmaf(tv, pb[r], acc1[r]);
        }
    }

    // ---- store: D (32x32) layout: col = lane&31 (pixel), row o = (r&3)+8*(r>>2)+4*g
    float* op = out + ((size_t)b * O_DIM) * (HW * HW) + (size_t)hout * HW + wout;
    #pragma unroll
    for (int r = 0; r < 16; ++r) {
        const int o = (r & 3) + ((r >> 2) << 3) + (g << 2);
        op[(size_t)o        * (HW * HW)] = acc0[r];
        op[(size_t)(o + 32) * (HW * HW)] = acc1[r];
    }
}

extern "C" void kernel_launch(void* const* d_in, const int* in_sizes, int n_in,
                              void* d_out, int out_size, void* d_ws, size_t ws_size,
                              hipStream_t stream) {
    const float* feat = (const float*)d_in[0];   // [8,64,128,128] f32
    const float* tm   = (const float*)d_in[1];   // [8,9,16384]    f32
    const float* W    = (const float*)d_in[2];   // [64,3,3,64]    f32
    float* out        = (float*)d_out;           // [8,64,128,128] f32
    unsigned short* Wf = (unsigned short*)d_ws;  // 73728 B scratch

    swizzle_W_kernel<<<dim3(144), dim3(256), 0, stream>>>(W, Wf);
    dyconv_kernel<<<dim3(1024), dim3(256), 0, stream>>>(feat, tm, Wf, out);
}